// Round 13
// baseline (357.538 us; speedup 1.0000x reference)
//
#include <hip/hip_runtime.h>
#include <math.h>

#define D 64

typedef __attribute__((ext_vector_type(8))) short bf16x8;
typedef __attribute__((ext_vector_type(4))) float f32x4;
typedef __fp16 fp16x2 __attribute__((ext_vector_type(2)));

static __device__ __forceinline__ unsigned short f2bf(float f) {
    unsigned int u = __float_as_uint(f);
    unsigned int r = (u + 0x7FFFu + ((u >> 16) & 1u)) >> 16;  // RNE
    return (unsigned short)r;
}
static __device__ __forceinline__ float bf2f(unsigned short h) {
    return __uint_as_float(((unsigned int)h) << 16);
}

#if defined(__has_builtin)
#if __has_builtin(__builtin_amdgcn_cvt_pk_bf16_f32)
#define HAVE_PK_BF16 1
#endif
#endif

static __device__ __forceinline__ unsigned int pk2bf(float a, float b) {
#ifdef HAVE_PK_BF16
    auto v = __builtin_amdgcn_cvt_pk_bf16_f32(a, b);   // low=a, high=b
    return *(unsigned int*)&v;
#else
    return (unsigned int)f2bf(a) | ((unsigned int)f2bf(b) << 16);
#endif
}

// packed fp16 (RTZ) from two floats: v_cvt_pkrtz_f16_f32
static __device__ __forceinline__ unsigned int pk2h(float a, float b) {
    fp16x2 v = __builtin_amdgcn_cvt_pkrtz(a, b);
    return *(unsigned int*)&v;
}

// tanh(x) = 1 - 2/(e^{2x}+1); inf-safe at extremes (no clamp needed)
static __device__ __forceinline__ float fast_tanh(float x) {
    float e = __expf(2.f * x);
    float r = __builtin_amdgcn_rcpf(e + 1.f);
    return 1.f - 2.f * r;
}

typedef __attribute__((address_space(1))) const unsigned int as1_uint;
typedef __attribute__((address_space(3))) unsigned int as3_uint;
static __device__ __forceinline__ void dma16(const void* g, void* l) {
    // async global->LDS, 16B/lane; LDS dest = uniform base + lane*16
    __builtin_amdgcn_global_load_lds((as1_uint*)g, (as3_uint*)l, 16, 0, 0);
}

// ---------------- one prep kernel, FOUR jobs:
// blocks [0,PB): by thread range:
//   jobB fb[n][m*4+c] = fp16(feat[n][c*16+m]);  jobC fh/fl bf16 hi/lo of feat;
//   jobA W -> B1/B2 frag hi/lo, W1/W2 -> F1/F2
// blocks [PB, PB+256): bucket histogram of dst (was k_bcount)
__global__ __launch_bounds__(256) void k_prep(const float* __restrict__ W,
                                              unsigned short* __restrict__ B1h,
                                              unsigned short* __restrict__ B1l,
                                              unsigned short* __restrict__ B2h,
                                              unsigned short* __restrict__ B2l,
                                              const float* __restrict__ W1,
                                              const float* __restrict__ W2,
                                              unsigned short* __restrict__ F1h,
                                              unsigned short* __restrict__ F1l,
                                              unsigned short* __restrict__ F2h,
                                              unsigned short* __restrict__ F2l,
                                              const float* __restrict__ feat,
                                              unsigned short* __restrict__ fb,
                                              unsigned short* __restrict__ fh,
                                              unsigned short* __restrict__ fl,
                                              const int* __restrict__ dst,
                                              int* __restrict__ cnt,
                                              int R, int N, int E, int CH,
                                              int NBUK, int PB) {
    if ((int)blockIdx.x >= PB) {
        // ---- bucket histogram role
        __shared__ int h[1024];
        const int t = threadIdx.x, blk = blockIdx.x - PB;
        for (int b = t; b < NBUK; b += 256) h[b] = 0;
        __syncthreads();
        const int s0 = blk * CH, s1 = min(E, s0 + CH);
        for (int e = s0 + t; e < s1; e += 256)
            atomicAdd(&h[dst[e] >> 7], 1);
        __syncthreads();
        for (int b = t; b < NBUK; b += 256)
            cnt[(b << 8) | blk] = h[b];
        return;
    }
    int idx = blockIdx.x * 256 + threadIdx.x;
    const int nb = N * 16;
    const int nc = N * 8;
    if (idx < nb) {
        int n = idx >> 4, k = idx & 15;
        union { _Float16 h[4]; uint2 u; } cv;
        #pragma unroll
        for (int c = 0; c < 4; ++c)
            cv.h[c] = (_Float16)feat[(size_t)n * D + c * 16 + k];
        *(uint2*)&fb[(size_t)n * D + k * 4] = cv.u;
        return;
    }
    idx -= nb;
    if (idx < nc) {
        int n = idx >> 3, ch = idx & 7;
        const float* p = feat + (size_t)n * D + ch * 8;
        float4 v0 = *(const float4*)p, v1 = *(const float4*)(p + 4);
        float vals[8] = {v0.x, v0.y, v0.z, v0.w, v1.x, v1.y, v1.z, v1.w};
        bf16x8 hv, lv;
        #pragma unroll
        for (int j = 0; j < 8; ++j) {
            unsigned short h = f2bf(vals[j]);
            hv[j] = (short)h;
            lv[j] = (short)f2bf(vals[j] - bf2f(h));
        }
        *(bf16x8*)&fh[(size_t)n * D + ch * 8] = hv;
        *(bf16x8*)&fl[(size_t)n * D + ch * 8] = lv;
        return;
    }
    idx -= nc;
    int per_g = R * 512;
    if (idx < 2 * per_g) {
        int g = idx / per_g;
        int rest = idx % per_g;
        int r = rest >> 9;
        int rest2 = rest & 511;
        int c = rest2 >> 7;
        int kb = (rest2 >> 6) & 1;
        int lane = rest2 & 63;
        int m = lane & 15, q = lane >> 4;
        bf16x8 hv, lv;
        #pragma unroll
        for (int j = 0; j < 8; ++j) {
            float v;
            if (g == 0) v = W[(size_t)r * 4096 + (kb * 32 + q * 8 + j) * 64 + (c * 16 + m)];
            else        v = W[(size_t)r * 4096 + (c * 16 + m) * 64 + (kb * 32 + q * 8 + j)];
            unsigned short h = f2bf(v);
            hv[j] = (short)h;
            lv[j] = (short)f2bf(v - bf2f(h));
        }
        size_t off = ((((size_t)r * 4 + c) * 2 + kb) * 64 + lane) * 8;
        unsigned short* ph = (g == 0) ? B1h : B2h;
        unsigned short* pl = (g == 0) ? B1l : B2l;
        *(bf16x8*)&ph[off] = hv;
        *(bf16x8*)&pl[off] = lv;
    } else {
        int idx2 = idx - 2 * per_g;
        if (idx2 >= 1024) return;
        int g = idx2 >> 9;
        int rest2 = idx2 & 511;
        int c = rest2 >> 7;
        int kb = (rest2 >> 6) & 1;
        int lane = rest2 & 63;
        int m = lane & 15, q = lane >> 4;
        const float* Wx = g ? W2 : W1;
        bf16x8 hv, lv;
        #pragma unroll
        for (int j = 0; j < 8; ++j) {
            float v = Wx[(c * 16 + m) * 64 + kb * 32 + q * 8 + j];
            unsigned short h = f2bf(v);
            hv[j] = (short)h;
            lv[j] = (short)f2bf(v - bf2f(h));
        }
        size_t off = (((size_t)c * 2 + kb) * 64 + lane) * 8;
        unsigned short* ph = g ? F2h : F1h;
        unsigned short* pl = g ? F2l : F1l;
        *(bf16x8*)&ph[off] = hv;
        *(bf16x8*)&pl[off] = lv;
    }
}

// ================= CSR build (bucket sort; scan2 eliminated — blocks rebuild
// the block-prefix of bsum in LDS themselves) =================================
#define NB3 256

// ---- scan step 1 (inclusive per-1024-block + block sums)
__global__ __launch_bounds__(1024) void k_scan1(const int* __restrict__ deg, int* __restrict__ tscan,
                                                int* __restrict__ bsum, int N) {
    __shared__ int s[1024];
    const int t = threadIdx.x;
    const int i = blockIdx.x * 1024 + t;
    int v = (i < N) ? deg[i] : 0;
    s[t] = v;
    __syncthreads();
    for (int off = 1; off < 1024; off <<= 1) {
        int tmp = (t >= off) ? s[t - off] : 0;
        __syncthreads();
        s[t] += tmp;
        __syncthreads();
    }
    if (i < N) tscan[i] = s[t];
    if (t == 1023) bsum[blockIdx.x] = s[1023];
}

// build exclusive prefix of bsum (NBS<=256) into sbp via 256-wide LDS scan
static __device__ __forceinline__ void build_sbp(const int* __restrict__ bsum,
                                                 int* ss, int* sbp, int NBS) {
    const int t = threadIdx.x;
    int v = (t < NBS) ? bsum[t] : 0;
    ss[t] = v;
    __syncthreads();
    for (int off = 1; off < 256; off <<= 1) {
        int tmp = (t >= off) ? ss[t - off] : 0;
        __syncthreads();
        ss[t] += tmp;
        __syncthreads();
    }
    sbp[t] = ss[t] - v;   // exclusive
    __syncthreads();
}

// ---- pass 2: scatter edges into bucket-grouped ebuf (deterministic bases)
// payload pack: src[0:20) | etype[20:25) | (dst&127)[25:32)
__global__ __launch_bounds__(256) void k_bscatter(const int* __restrict__ src,
                                                  const int* __restrict__ dst,
                                                  const int* __restrict__ etype,
                                                  const int* __restrict__ tsc,
                                                  const int* __restrict__ bsum,
                                                  int* __restrict__ ebuf,
                                                  int E, int CH, int NBUK, int NBS) {
    __shared__ int cur[1024];
    __shared__ int ss[256];
    __shared__ int sbp[256];
    const int t = threadIdx.x, blk = blockIdx.x;
    build_sbp(bsum, ss, sbp, NBS);
    for (int b = t; b < NBUK; b += 256) {
        int i = (b << 8) | blk;
        cur[b] = (i == 0) ? 0 : (tsc[i - 1] + sbp[(i - 1) >> 10]);
    }
    __syncthreads();
    const int s0 = blk * CH, s1 = min(E, s0 + CH);
    for (int e = s0 + t; e < s1; e += 256) {
        int d = dst[e];
        int b = d >> 7;
        int pos = atomicAdd(&cur[b], 1);
        unsigned int pk = (unsigned int)src[e] | ((unsigned int)etype[e] << 20)
                        | ((unsigned int)(d & 127) << 25);
        ebuf[pos] = (int)pk;
    }
}

// ---- pass 3: one block per bucket: degree + prefix -> offsets, then scatter
__global__ __launch_bounds__(256) void k_bcsr(const int* __restrict__ ebuf,
                                              const int* __restrict__ tsc,
                                              const int* __restrict__ bsum,
                                              int* __restrict__ offsets,
                                              int* __restrict__ spack,
                                              int N, int E, int NBUK, int NBS) {
    __shared__ int sdeg[128], sincl[128], scur[128];
    __shared__ int ss[256];
    __shared__ int sbp[256];
    const int t = threadIdx.x, b = blockIdx.x;
    build_sbp(bsum, ss, sbp, NBS);
    int i0 = b << 8;
    int i1 = (b + 1) << 8;
    const int s0 = (i0 == 0) ? 0 : (tsc[i0 - 1] + sbp[(i0 - 1) >> 10]);
    const int s1 = tsc[i1 - 1] + sbp[(i1 - 1) >> 10];
    if (t < 128) { sdeg[t] = 0; }
    __syncthreads();
    for (int e = s0 + t; e < s1; e += 256)
        atomicAdd(&sdeg[((unsigned int)ebuf[e]) >> 25], 1);
    __syncthreads();
    if (t < 128) sincl[t] = sdeg[t];
    __syncthreads();
    for (int off = 1; off < 128; off <<= 1) {
        int v = 0;
        if (t < 128 && t >= off) v = sincl[t - off];
        __syncthreads();
        if (t < 128) sincl[t] += v;
        __syncthreads();
    }
    if (t < 128) {
        int excl = sincl[t] - sdeg[t];
        scur[t] = s0 + excl;
        int n = (b << 7) + t;
        if (n < N) offsets[n] = s0 + excl;
    }
    if (b == NBUK - 1 && t == 0) offsets[N] = E;
    __syncthreads();
    for (int e = s0 + t; e < s1; e += 256) {
        unsigned int pk = (unsigned int)ebuf[e];
        int i = pk >> 25;
        int p = atomicAdd(&scur[i], 1);
        spack[p] = (int)(pk & 0x01FFFFFFu);
    }
}

// ---------------- fused proj+V, r-quartered grid (tile x r-quarter blocks).
__global__ __launch_bounds__(256, 4) void k_projv(const unsigned short* __restrict__ fh,
                                                  const unsigned short* __restrict__ fl,
                                                  const unsigned short* __restrict__ B1h,
                                                  const unsigned short* __restrict__ B1l,
                                                  const unsigned short* __restrict__ B2h,
                                                  const unsigned short* __restrict__ B2l,
                                                  const float* __restrict__ emb,
                                                  unsigned short* __restrict__ V,
                                                  int N, int R, int nrq) {
    const int tile = blockIdx.x / nrq;
    const int rq   = blockIdx.x % nrq;
    const int rbase = rq * 4;
    const int rcnt  = (R - rbase < 4) ? (R - rbase) : 4;
    const int n0 = tile * 128;
    __shared__ __align__(16) unsigned short Bbuf[32][512];   // 32 KB
    __shared__ __align__(16) unsigned short Us[4][1024];     // 8 KB (per-s, wave-private)
    const int t = threadIdx.x;
    const int lane = t & 63, w = t >> 6;
    const int m = lane & 15, q = lane >> 4;

    // ---- A-frags: plain 16B loads of pre-split bf16 hi/lo
    bf16x8 ah[2][2], al[2][2];
    #pragma unroll
    for (int s = 0; s < 2; ++s) {
        int n = n0 + w * 32 + s * 16 + m;
        bool ok = n < N;
        #pragma unroll
        for (int kb = 0; kb < 2; ++kb) {
            int d0 = kb * 32 + q * 8;
            if (ok) {
                ah[s][kb] = *(const bf16x8*)&fh[(size_t)n * D + d0];
                al[s][kb] = *(const bf16x8*)&fl[(size_t)n * D + d0];
            } else {
                #pragma unroll
                for (int j = 0; j < 8; ++j) { ah[s][kb][j] = 0; al[s][kb][j] = 0; }
            }
        }
    }

    auto stage_half = [&](int r, int half) {
        const unsigned short* arr = half ? ((w < 2) ? B2h : B2l)
                                         : ((w < 2) ? B1h : B1l);
        const unsigned short* gp = arr + (size_t)r * 4096 + (size_t)(w & 1) * 2048 + lane * 8;
        unsigned short* lp = &Bbuf[half * 16 + (w >> 1) * 8 + (w & 1) * 4][0];
        #pragma unroll
        for (int i = 0; i < 4; ++i)
            dma16(gp + i * 512, lp + i * 512);
    };

    stage_half(rbase, 0);
    stage_half(rbase, 1);
    __syncthreads();

    for (int rr = 0; rr < rcnt; ++rr) {
        const int r = rbase + rr;
        float em[4];
        #pragma unroll
        for (int c = 0; c < 4; ++c) em[c] = emb[r * 64 + c * 16 + m];

        // ---------- GEMM1 (both s): P = feat @ W_r (3-term split), B-frags hoisted
        f32x4 acc[4][2];
        #pragma unroll
        for (int c = 0; c < 4; ++c)
            #pragma unroll
            for (int s = 0; s < 2; ++s) acc[c][s] = (f32x4){0.f, 0.f, 0.f, 0.f};
        #pragma unroll
        for (int c = 0; c < 4; ++c) {
            bf16x8 bh[2], bl[2];
            #pragma unroll
            for (int kb = 0; kb < 2; ++kb) {
                bh[kb] = *(const bf16x8*)&Bbuf[c * 2 + kb][lane * 8];
                bl[kb] = *(const bf16x8*)&Bbuf[8 + c * 2 + kb][lane * 8];
            }
            #pragma unroll
            for (int s = 0; s < 2; ++s)
                #pragma unroll
                for (int kb = 0; kb < 2; ++kb) {
                    acc[c][s] = __builtin_amdgcn_mfma_f32_16x16x32_bf16(ah[s][kb], bh[kb], acc[c][s], 0, 0, 0);
                    acc[c][s] = __builtin_amdgcn_mfma_f32_16x16x32_bf16(al[s][kb], bh[kb], acc[c][s], 0, 0, 0);
                    acc[c][s] = __builtin_amdgcn_mfma_f32_16x16x32_bf16(ah[s][kb], bl[kb], acc[c][s], 0, 0, 0);
                }
        }

        __syncthreads();                         // rows 0-15 consumed
        if (rr + 1 < rcnt) stage_half(r + 1, 0); // B1(r+1) DMA overlaps epi+GEMM2

        // ---------- per-s: epilogue -> Us, GEMM2, store
        #pragma unroll
        for (int s = 0; s < 2; ++s) {
            #pragma unroll
            for (int c = 0; c < 4; ++c) {
                int o = c * 16 + m;
                int kb2 = o >> 5;
                int q2 = (o >> 3) & 3;
                int j = o & 7;
                int Fb = kb2 * 64 + q2 * 16 + q * 4;
                #pragma unroll
                for (int i = 0; i < 4; i += 2) {
                    float t0 = fast_tanh(acc[c][s][i] + em[c]);
                    float t1 = fast_tanh(acc[c][s][i + 1] + em[c]);
                    unsigned int pk = pk2bf(t0, t1);
                    Us[w][((Fb + i) ^ q2) * 8 + j]     = (unsigned short)(pk & 0xFFFF);
                    Us[w][((Fb + i + 1) ^ q2) * 8 + j] = (unsigned short)(pk >> 16);
                }
            }

            bf16x8 ua[2];
            #pragma unroll
            for (int kb = 0; kb < 2; ++kb) {
                int F = kb * 64 + lane;
                ua[kb] = *(const bf16x8*)&Us[w][(F ^ (lane >> 4)) * 8];
            }
            f32x4 acc2[4];
            #pragma unroll
            for (int c = 0; c < 4; ++c) acc2[c] = (f32x4){0.f, 0.f, 0.f, 0.f};
            #pragma unroll
            for (int c = 0; c < 4; ++c) {
                bf16x8 bh[2], bl[2];
                #pragma unroll
                for (int kb = 0; kb < 2; ++kb) {
                    bh[kb] = *(const bf16x8*)&Bbuf[16 + c * 2 + kb][lane * 8];
                    bl[kb] = *(const bf16x8*)&Bbuf[24 + c * 2 + kb][lane * 8];
                }
                #pragma unroll
                for (int kb = 0; kb < 2; ++kb) {
                    acc2[c] = __builtin_amdgcn_mfma_f32_16x16x32_bf16(ua[kb], bh[kb], acc2[c], 0, 0, 0);
                    acc2[c] = __builtin_amdgcn_mfma_f32_16x16x32_bf16(ua[kb], bl[kb], acc2[c], 0, 0, 0);
                }
            }

            #pragma unroll
            for (int i = 0; i < 4; ++i) {
                int n = n0 + w * 32 + s * 16 + q * 4 + i;
                if (n < N) {
                    uint2 pv;
                    pv.x = pk2h(acc2[0][i], acc2[1][i]);   // fp16 pack (RTZ)
                    pv.y = pk2h(acc2[2][i], acc2[3][i]);
                    *(uint2*)&V[((size_t)n * R + r) * 64 + m * 4] = pv;
                }
            }
        }

        __syncthreads();                         // rows 16-31 consumed; half-0 DMA drained
        if (rr + 1 < rcnt) stage_half(r + 1, 1); // B2(r+1) DMA overlaps next GEMM1
    }
}

// ---------------- fused att + softmax + aggregation, v4 (fixed):
// 4 lanes per edge (lane = ei*4+sub): 16 edges/chunk in one shot.
// Chunk-sum butterfly covers lane-bits 2..5 only, which already yields
// sum-over-16-edges per lane (wgt is sub-uniform) -> NO 0.25 factor.
__global__ __launch_bounds__(256) void k_fused2(const unsigned short* __restrict__ V,
                                                const unsigned short* __restrict__ fb,
                                                const int* __restrict__ offsets,
                                                const int* __restrict__ spack,
                                                float* __restrict__ h_nb,
                                                int N, int R) {
    const int lane = threadIdx.x & 63;
    const int wav  = threadIdx.x >> 6;
    const int ei   = lane >> 2;      // edge-in-chunk 0..15
    const int sub  = lane & 3;       // 16-channel slice
    const int n = blockIdx.x * 4 + wav;
    __shared__ __align__(16) unsigned short vlds[4][1024];   // raw fp16 V, 2KB/wave
    __shared__ __align__(16) float rlds[4][64 * 20];         // epilogue scratch (pad 20)

    if (n < N) {
        const unsigned short* gp = V + (size_t)n * 1024 + lane * 8;
        dma16(gp,       &vlds[wav][0]);
        dma16(gp + 512, &vlds[wav][512]);
    }
    __syncthreads();
    if (n >= N) return;

    const int beg = offsets[n], end = offsets[n + 1];
    float m = -INFINITY, l = 0.f;
    float acc[16];
    #pragma unroll
    for (int i = 0; i < 16; ++i) acc[i] = 0.f;

    for (int cbeg = beg; cbeg < end; cbeg += 16) {
        int e = cbeg + ei;
        bool ok = e < end;
        int pk = spack[ok ? e : end - 1];
        unsigned int fo = (unsigned int)(pk & 0xFFFFF) * D + sub * 16;
        int et = pk >> 20;
        union { uint4 u[2]; fp16x2 h2[8]; _Float16 s[16]; } cf, vv;
        cf.u[0] = *(const uint4*)&fb[fo];
        cf.u[1] = *(const uint4*)&fb[fo + 8];
        vv.u[0] = *(const uint4*)&vlds[wav][et * 64 + sub * 16];
        vv.u[1] = *(const uint4*)&vlds[wav][et * 64 + sub * 16 + 8];
        // two independent fdot2 chains of 4
        float d0 = __builtin_amdgcn_fdot2(cf.h2[0], vv.h2[0], 0.f, false);
        d0 = __builtin_amdgcn_fdot2(cf.h2[1], vv.h2[1], d0, false);
        d0 = __builtin_amdgcn_fdot2(cf.h2[2], vv.h2[2], d0, false);
        d0 = __builtin_amdgcn_fdot2(cf.h2[3], vv.h2[3], d0, false);
        float d1 = __builtin_amdgcn_fdot2(cf.h2[4], vv.h2[4], 0.f, false);
        d1 = __builtin_amdgcn_fdot2(cf.h2[5], vv.h2[5], d1, false);
        d1 = __builtin_amdgcn_fdot2(cf.h2[6], vv.h2[6], d1, false);
        d1 = __builtin_amdgcn_fdot2(cf.h2[7], vv.h2[7], d1, false);
        float d = d0 + d1;
        d += __shfl_xor(d, 1, 64);
        d += __shfl_xor(d, 2, 64);          // all 4 lanes of edge have logit
        d = ok ? d : -INFINITY;
        // chunk max over 16 edges (wave-uniform result)
        float cm = fmaxf(d, __shfl_xor(d, 4, 64));
        cm = fmaxf(cm, __shfl_xor(cm, 8, 64));
        cm = fmaxf(cm, __shfl_xor(cm, 16, 64));
        cm = fmaxf(cm, __shfl_xor(cm, 32, 64));
        float nm = fmaxf(m, cm);
        float wgt = __expf(d - nm);          // invalid lanes -> 0
        // butterfly over ei bits (4,8,16,32): each lane ends with sum over the
        // 16 edges (wgt is sub-uniform) — exactly the chunk sum, no overcount
        float cs = wgt + __shfl_xor(wgt, 4, 64);
        cs += __shfl_xor(cs, 8, 64);
        cs += __shfl_xor(cs, 16, 64);
        cs += __shfl_xor(cs, 32, 64);
        if (nm != m) {                       // wave-uniform rescale (skip if max unchanged)
            float scale = __expf(m - nm);
            l *= scale;
            #pragma unroll
            for (int i = 0; i < 16; ++i) acc[i] *= scale;
            m = nm;
        }
        l += cs;
        #pragma unroll
        for (int i = 0; i < 16; ++i)
            acc[i] += wgt * (float)cf.s[i];
    }

    // epilogue: per-lane acc -> LDS (channel-major rows, pad 20), row-sum, store
    #pragma unroll
    for (int i = 0; i < 16; ++i) {
        int ch = (i & 3) * 16 + sub * 4 + (i >> 2);
        rlds[wav][ch * 20 + ei] = acc[i];
    }
    const float* row = &rlds[wav][lane * 20];
    float4 r0 = *(const float4*)row;
    float4 r1 = *(const float4*)(row + 4);
    float4 r2 = *(const float4*)(row + 8);
    float4 r3 = *(const float4*)(row + 12);
    float s = ((r0.x + r0.y) + (r0.z + r0.w)) + ((r1.x + r1.y) + (r1.z + r1.w))
            + ((r2.x + r2.y) + (r2.z + r2.w)) + ((r3.x + r3.y) + (r3.z + r3.w));
    float inv = (l != 0.f) ? 1.f / l : 0.f;
    h_nb[(size_t)n * D + lane] = s * inv;
}

// ---------------- final via MFMA: out = lrelu((f+h)@W1^T) + lrelu((f*h)@W2^T)
__global__ __launch_bounds__(256, 2) void k_final(const float* __restrict__ feat,
                                                  const float* __restrict__ h_nb,
                                                  const unsigned short* __restrict__ F1h,
                                                  const unsigned short* __restrict__ F1l,
                                                  const unsigned short* __restrict__ F2h,
                                                  const unsigned short* __restrict__ F2l,
                                                  float* __restrict__ out, int N) {
    const int n0 = blockIdx.x * 128;
    __shared__ __align__(16) unsigned short Wlds[4][4096];
    const int t = threadIdx.x;
    const int lane = t & 63, w = t >> 6;
    const int m = lane & 15, q = lane >> 4;

    const unsigned short* warr = (w == 0) ? F1h : (w == 1) ? F1l : (w == 2) ? F2h : F2l;
    #pragma unroll
    for (int i = 0; i < 8; ++i)
        dma16(warr + i * 512 + lane * 8, &Wlds[w][i * 512]);

    bf16x8 sh[2][2], sl[2][2], ph[2][2], pl[2][2];
    #pragma unroll
    for (int s = 0; s < 2; ++s) {
        int n = n0 + w * 32 + s * 16 + m;
        const float* fp = feat + (size_t)n * D;
        const float* hp = h_nb + (size_t)n * D;
        #pragma unroll
        for (int kb = 0; kb < 2; ++kb) {
            int d0 = kb * 32 + q * 8;
            float4 f0 = make_float4(0.f, 0.f, 0.f, 0.f), f1 = f0, h0 = f0, h1 = f0;
            if (n < N) {
                f0 = *(const float4*)(fp + d0); f1 = *(const float4*)(fp + d0 + 4);
                h0 = *(const float4*)(hp + d0); h1 = *(const float4*)(hp + d0 + 4);
            }
            float fv[8] = {f0.x, f0.y, f0.z, f0.w, f1.x, f1.y, f1.z, f1.w};
            float hv[8] = {h0.x, h0.y, h0.z, h0.w, h1.x, h1.y, h1.z, h1.w};
            bf16x8 a, b, c2, d2;
            #pragma unroll
            for (int j = 0; j < 8; ++j) {
                float xs = fv[j] + hv[j];
                float xp = fv[j] * hv[j];
                unsigned short hs = f2bf(xs);
                unsigned short hp2 = f2bf(xp);
                a[j]  = (short)hs;
                b[j]  = (short)f2bf(xs - bf2f(hs));
                c2[j] = (short)hp2;
                d2[j] = (short)f2bf(xp - bf2f(hp2));
            }
            sh[s][kb] = a; sl[s][kb] = b; ph[s][kb] = c2; pl[s][kb] = d2;
        }
    }
    __syncthreads();

    f32x4 a1[4][2], a2[4][2];
    #pragma unroll
    for (int c = 0; c < 4; ++c)
        #pragma unroll
        for (int s = 0; s < 2; ++s) {
            a1[c][s] = (f32x4){0.f, 0.f, 0.f, 0.f};
            a2[c][s] = (f32x4){0.f, 0.f, 0.f, 0.f};
        }
    #pragma unroll
    for (int c = 0; c < 4; ++c) {
        bf16x8 b1h[2], b1l[2], b2h[2], b2l[2];
        #pragma unroll
        for (int kb = 0; kb < 2; ++kb) {
            int o = (c * 2 + kb) * 512 + lane * 8;
            b1h[kb] = *(const bf16x8*)&Wlds[0][o];
            b1l[kb] = *(const bf16x8*)&Wlds[1][o];
            b2h[kb] = *(const bf16x8*)&Wlds[2][o];
            b2l[kb] = *(const bf16x8*)&Wlds[3][o];
        }
        #pragma unroll
        for (int kb = 0; kb < 2; ++kb)
            #pragma unroll
            for (int s = 0; s < 2; ++s) {
                a1[c][s] = __builtin_amdgcn_mfma_f32_16x16x32_bf16(sh[s][kb], b1h[kb], a1[c][s], 0, 0, 0);
                a1[c][s] = __builtin_amdgcn_mfma_f32_16x16x32_bf16(sl[s][kb], b1h[kb], a1[c][s], 0, 0, 0);
                a1[c][s] = __builtin_amdgcn_mfma_f32_16x16x32_bf16(sh[s][kb], b1l[kb], a1[c][s], 0, 0, 0);
                a2[c][s] = __builtin_amdgcn_mfma_f32_16x16x32_bf16(ph[s][kb], b2h[kb], a2[c][s], 0, 0, 0);
                a2[c][s] = __builtin_amdgcn_mfma_f32_16x16x32_bf16(pl[s][kb], b2h[kb], a2[c][s], 0, 0, 0);
                a2[c][s] = __builtin_amdgcn_mfma_f32_16x16x32_bf16(ph[s][kb], b2l[kb], a2[c][s], 0, 0, 0);
            }
    }

    #pragma unroll
    for (int s = 0; s < 2; ++s)
        #pragma unroll
        for (int i = 0; i < 4; ++i) {
            int n = n0 + w * 32 + s * 16 + q * 4 + i;
            if (n < N) {
                #pragma unroll
                for (int c = 0; c < 4; ++c) {
                    float o1 = a1[c][s][i];
                    float o2 = a2[c][s][i];
                    o1 = (o1 > 0.f) ? o1 : 0.01f * o1;
                    o2 = (o2 > 0.f) ? o2 : 0.01f * o2;
                    out[(size_t)n * D + c * 16 + m] = o1 + o2;
                }
            }
        }
}

extern "C" void kernel_launch(void* const* d_in, const int* in_sizes, int n_in,
                              void* d_out, int out_size, void* d_ws, size_t ws_size,
                              hipStream_t stream) {
    const float* feat  = (const float*)d_in[0];
    const float* relW  = (const float*)d_in[1];
    const float* relE  = (const float*)d_in[2];
    const float* W1    = (const float*)d_in[3];
    const float* W2    = (const float*)d_in[4];
    const int*   src   = (const int*)d_in[5];
    const int*   dst   = (const int*)d_in[6];
    const int*   etype = (const int*)d_in[7];
    float* out = (float*)d_out;

    const int N = in_sizes[0] / D;
    const int R = in_sizes[2] / D;
    const int E = in_sizes[5];

    char* w = (char*)d_ws;
    size_t off = 0;
    auto alloc = [&](size_t bytes) -> void* {
        void* p = w + off;
        off = (off + bytes + 255) & ~(size_t)255;
        return p;
    };
    unsigned short* varr = (unsigned short*)alloc((size_t)N * R * D * sizeof(unsigned short));
    float* h_nb   = (float*)alloc((size_t)N * D * sizeof(float));
    int* offsets  = (int*)alloc((size_t)(N + 1) * sizeof(int));
    int* bsum     = (int*)alloc(2048 * sizeof(int));
    int* spack    = (int*)alloc((size_t)E * sizeof(int));
    unsigned short* fb = (unsigned short*)alloc((size_t)N * D * sizeof(unsigned short));
    size_t wfrag = (size_t)R * 4 * 2 * 64 * 8;
    unsigned short* B1h = (unsigned short*)alloc(wfrag * sizeof(unsigned short));
    unsigned short* B1l = (unsigned short*)alloc(wfrag * sizeof(unsigned short));
    unsigned short* B2h = (unsigned short*)alloc(wfrag * sizeof(unsigned short));
    unsigned short* B2l = (unsigned short*)alloc(wfrag * sizeof(unsigned short));
    unsigned short* F1h = (unsigned short*)alloc(4096 * sizeof(unsigned short));
    unsigned short* F1l = (unsigned short*)alloc(4096 * sizeof(unsigned short));
    unsigned short* F2h = (unsigned short*)alloc(4096 * sizeof(unsigned short));
    unsigned short* F2l = (unsigned short*)alloc(4096 * sizeof(unsigned short));
    (void)ws_size; (void)n_in; (void)out_size;

    // ---- fh/fl (bf16 hi/lo feat) alias h_nb (dead until k_fused2 writes it)
    unsigned short* fh = (unsigned short*)h_nb;            // N*D shorts
    unsigned short* fl = fh + (size_t)N * D;               // N*D shorts

    // ---- CSR scratch aliases varr (dead before k_projv writes varr)
    const int NBUK = (N + 127) >> 7;           // buckets of 128 nodes (<=1024)
    const int CH   = (E + NB3 - 1) / NB3;      // edges per chunk
    const int L    = NBUK << 8;                // cnt length (NB3=256)
    int* ebuf = (int*)varr;                    // E ints
    int* cnt  = ebuf + E;                      // L ints
    int* tsc  = cnt + L;                       // L ints
    const int NBscan = (L + 1023) / 1024;      // <=256 (NBUK<=1024)

    const int nrq = (R + 3) / 4;               // r-quarters per tile
    const int ntiles = (N + 127) / 128;
    const int nPrep = N * 16 + N * 8 + 2 * R * 512 + 1024;
    const int PB = (nPrep + 255) / 256;

    k_prep<<<PB + NB3, 256, 0, stream>>>(relW, B1h, B1l, B2h, B2l,
                                         W1, W2, F1h, F1l, F2h, F2l,
                                         feat, fb, fh, fl,
                                         dst, cnt, R, N, E, CH, NBUK, PB);
    k_scan1<<<NBscan, 1024, 0, stream>>>(cnt, tsc, bsum, L);
    k_bscatter<<<NB3, 256, 0, stream>>>(src, dst, etype, tsc, bsum, ebuf, E, CH, NBUK, NBscan);
    k_bcsr<<<NBUK, 256, 0, stream>>>(ebuf, tsc, bsum, offsets, spack, N, E, NBUK, NBscan);
    k_projv<<<ntiles * nrq, 256, 0, stream>>>(fh, fl, B1h, B1l, B2h, B2l, relE, varr, N, R, nrq);
    k_fused2<<<(N + 3) / 4, 256, 0, stream>>>(varr, fb, offsets, spack, h_nb, N, R);
    k_final<<<(N + 127) / 128, 256, 0, stream>>>(feat, h_nb, F1h, F1l, F2h, F2l, out, N);
}

// Round 14
// 339.426 us; speedup vs baseline: 1.0534x; 1.0534x over previous
//
#include <hip/hip_runtime.h>
#include <math.h>

#define D 64

typedef __attribute__((ext_vector_type(8))) short bf16x8;
typedef __attribute__((ext_vector_type(4))) float f32x4;
typedef __fp16 fp16x2 __attribute__((ext_vector_type(2)));

static __device__ __forceinline__ unsigned short f2bf(float f) {
    unsigned int u = __float_as_uint(f);
    unsigned int r = (u + 0x7FFFu + ((u >> 16) & 1u)) >> 16;  // RNE
    return (unsigned short)r;
}
static __device__ __forceinline__ float bf2f(unsigned short h) {
    return __uint_as_float(((unsigned int)h) << 16);
}

#if defined(__has_builtin)
#if __has_builtin(__builtin_amdgcn_cvt_pk_bf16_f32)
#define HAVE_PK_BF16 1
#endif
#endif

static __device__ __forceinline__ unsigned int pk2bf(float a, float b) {
#ifdef HAVE_PK_BF16
    auto v = __builtin_amdgcn_cvt_pk_bf16_f32(a, b);   // low=a, high=b
    return *(unsigned int*)&v;
#else
    return (unsigned int)f2bf(a) | ((unsigned int)f2bf(b) << 16);
#endif
}

// packed fp16 (RTZ) from two floats: v_cvt_pkrtz_f16_f32
static __device__ __forceinline__ unsigned int pk2h(float a, float b) {
    fp16x2 v = __builtin_amdgcn_cvt_pkrtz(a, b);
    return *(unsigned int*)&v;
}

// tanh(x) = 1 - 2/(e^{2x}+1); inf-safe at extremes (no clamp needed)
static __device__ __forceinline__ float fast_tanh(float x) {
    float e = __expf(2.f * x);
    float r = __builtin_amdgcn_rcpf(e + 1.f);
    return 1.f - 2.f * r;
}

typedef __attribute__((address_space(1))) const unsigned int as1_uint;
typedef __attribute__((address_space(3))) unsigned int as3_uint;
static __device__ __forceinline__ void dma16(const void* g, void* l) {
    // async global->LDS, 16B/lane; LDS dest = uniform base + lane*16
    __builtin_amdgcn_global_load_lds((as1_uint*)g, (as3_uint*)l, 16, 0, 0);
}

// ---------------- one prep kernel, FOUR jobs:
// blocks [0,PB): by thread range:
//   jobB fb[n][m*4+c] = fp16(feat[n][c*16+m]);  jobC fh/fl bf16 hi/lo of feat;
//   jobA W -> B1/B2 frag hi/lo, W1/W2 -> F1/F2
// blocks [PB, PB+256): bucket histogram of dst (was k_bcount)
__global__ __launch_bounds__(256) void k_prep(const float* __restrict__ W,
                                              unsigned short* __restrict__ B1h,
                                              unsigned short* __restrict__ B1l,
                                              unsigned short* __restrict__ B2h,
                                              unsigned short* __restrict__ B2l,
                                              const float* __restrict__ W1,
                                              const float* __restrict__ W2,
                                              unsigned short* __restrict__ F1h,
                                              unsigned short* __restrict__ F1l,
                                              unsigned short* __restrict__ F2h,
                                              unsigned short* __restrict__ F2l,
                                              const float* __restrict__ feat,
                                              unsigned short* __restrict__ fb,
                                              unsigned short* __restrict__ fh,
                                              unsigned short* __restrict__ fl,
                                              const int* __restrict__ dst,
                                              int* __restrict__ cnt,
                                              int R, int N, int E, int CH,
                                              int NBUK, int PB) {
    if ((int)blockIdx.x >= PB) {
        // ---- bucket histogram role
        __shared__ int h[1024];
        const int t = threadIdx.x, blk = blockIdx.x - PB;
        for (int b = t; b < NBUK; b += 256) h[b] = 0;
        __syncthreads();
        const int s0 = blk * CH, s1 = min(E, s0 + CH);
        for (int e = s0 + t; e < s1; e += 256)
            atomicAdd(&h[dst[e] >> 7], 1);
        __syncthreads();
        for (int b = t; b < NBUK; b += 256)
            cnt[(b << 8) | blk] = h[b];
        return;
    }
    int idx = blockIdx.x * 256 + threadIdx.x;
    const int nb = N * 16;
    const int nc = N * 8;
    if (idx < nb) {
        int n = idx >> 4, k = idx & 15;
        union { _Float16 h[4]; uint2 u; } cv;
        #pragma unroll
        for (int c = 0; c < 4; ++c)
            cv.h[c] = (_Float16)feat[(size_t)n * D + c * 16 + k];
        *(uint2*)&fb[(size_t)n * D + k * 4] = cv.u;
        return;
    }
    idx -= nb;
    if (idx < nc) {
        int n = idx >> 3, ch = idx & 7;
        const float* p = feat + (size_t)n * D + ch * 8;
        float4 v0 = *(const float4*)p, v1 = *(const float4*)(p + 4);
        float vals[8] = {v0.x, v0.y, v0.z, v0.w, v1.x, v1.y, v1.z, v1.w};
        bf16x8 hv, lv;
        #pragma unroll
        for (int j = 0; j < 8; ++j) {
            unsigned short h = f2bf(vals[j]);
            hv[j] = (short)h;
            lv[j] = (short)f2bf(vals[j] - bf2f(h));
        }
        *(bf16x8*)&fh[(size_t)n * D + ch * 8] = hv;
        *(bf16x8*)&fl[(size_t)n * D + ch * 8] = lv;
        return;
    }
    idx -= nc;
    int per_g = R * 512;
    if (idx < 2 * per_g) {
        int g = idx / per_g;
        int rest = idx % per_g;
        int r = rest >> 9;
        int rest2 = rest & 511;
        int c = rest2 >> 7;
        int kb = (rest2 >> 6) & 1;
        int lane = rest2 & 63;
        int m = lane & 15, q = lane >> 4;
        bf16x8 hv, lv;
        #pragma unroll
        for (int j = 0; j < 8; ++j) {
            float v;
            if (g == 0) v = W[(size_t)r * 4096 + (kb * 32 + q * 8 + j) * 64 + (c * 16 + m)];
            else        v = W[(size_t)r * 4096 + (c * 16 + m) * 64 + (kb * 32 + q * 8 + j)];
            unsigned short h = f2bf(v);
            hv[j] = (short)h;
            lv[j] = (short)f2bf(v - bf2f(h));
        }
        size_t off = ((((size_t)r * 4 + c) * 2 + kb) * 64 + lane) * 8;
        unsigned short* ph = (g == 0) ? B1h : B2h;
        unsigned short* pl = (g == 0) ? B1l : B2l;
        *(bf16x8*)&ph[off] = hv;
        *(bf16x8*)&pl[off] = lv;
    } else {
        int idx2 = idx - 2 * per_g;
        if (idx2 >= 1024) return;
        int g = idx2 >> 9;
        int rest2 = idx2 & 511;
        int c = rest2 >> 7;
        int kb = (rest2 >> 6) & 1;
        int lane = rest2 & 63;
        int m = lane & 15, q = lane >> 4;
        const float* Wx = g ? W2 : W1;
        bf16x8 hv, lv;
        #pragma unroll
        for (int j = 0; j < 8; ++j) {
            float v = Wx[(c * 16 + m) * 64 + kb * 32 + q * 8 + j];
            unsigned short h = f2bf(v);
            hv[j] = (short)h;
            lv[j] = (short)f2bf(v - bf2f(h));
        }
        size_t off = (((size_t)c * 2 + kb) * 64 + lane) * 8;
        unsigned short* ph = g ? F2h : F1h;
        unsigned short* pl = g ? F2l : F1l;
        *(bf16x8*)&ph[off] = hv;
        *(bf16x8*)&pl[off] = lv;
    }
}

// ================= CSR build (bucket sort; scan2 eliminated — blocks rebuild
// the block-prefix of bsum in LDS themselves) =================================
#define NB3 256

// ---- scan step 1 (inclusive per-1024-block + block sums)
__global__ __launch_bounds__(1024) void k_scan1(const int* __restrict__ deg, int* __restrict__ tscan,
                                                int* __restrict__ bsum, int N) {
    __shared__ int s[1024];
    const int t = threadIdx.x;
    const int i = blockIdx.x * 1024 + t;
    int v = (i < N) ? deg[i] : 0;
    s[t] = v;
    __syncthreads();
    for (int off = 1; off < 1024; off <<= 1) {
        int tmp = (t >= off) ? s[t - off] : 0;
        __syncthreads();
        s[t] += tmp;
        __syncthreads();
    }
    if (i < N) tscan[i] = s[t];
    if (t == 1023) bsum[blockIdx.x] = s[1023];
}

// build exclusive prefix of bsum (NBS<=256) into sbp via 256-wide LDS scan
static __device__ __forceinline__ void build_sbp(const int* __restrict__ bsum,
                                                 int* ss, int* sbp, int NBS) {
    const int t = threadIdx.x;
    int v = (t < NBS) ? bsum[t] : 0;
    ss[t] = v;
    __syncthreads();
    for (int off = 1; off < 256; off <<= 1) {
        int tmp = (t >= off) ? ss[t - off] : 0;
        __syncthreads();
        ss[t] += tmp;
        __syncthreads();
    }
    sbp[t] = ss[t] - v;   // exclusive
    __syncthreads();
}

// ---- pass 2: scatter edges into bucket-grouped ebuf (deterministic bases)
// payload pack: src[0:20) | etype[20:25) | (dst&127)[25:32)
__global__ __launch_bounds__(256) void k_bscatter(const int* __restrict__ src,
                                                  const int* __restrict__ dst,
                                                  const int* __restrict__ etype,
                                                  const int* __restrict__ tsc,
                                                  const int* __restrict__ bsum,
                                                  int* __restrict__ ebuf,
                                                  int E, int CH, int NBUK, int NBS) {
    __shared__ int cur[1024];
    __shared__ int ss[256];
    __shared__ int sbp[256];
    const int t = threadIdx.x, blk = blockIdx.x;
    build_sbp(bsum, ss, sbp, NBS);
    for (int b = t; b < NBUK; b += 256) {
        int i = (b << 8) | blk;
        cur[b] = (i == 0) ? 0 : (tsc[i - 1] + sbp[(i - 1) >> 10]);
    }
    __syncthreads();
    const int s0 = blk * CH, s1 = min(E, s0 + CH);
    for (int e = s0 + t; e < s1; e += 256) {
        int d = dst[e];
        int b = d >> 7;
        int pos = atomicAdd(&cur[b], 1);
        unsigned int pk = (unsigned int)src[e] | ((unsigned int)etype[e] << 20)
                        | ((unsigned int)(d & 127) << 25);
        ebuf[pos] = (int)pk;
    }
}

// ---- pass 3: one block per bucket: degree + prefix -> offsets, then scatter
__global__ __launch_bounds__(256) void k_bcsr(const int* __restrict__ ebuf,
                                              const int* __restrict__ tsc,
                                              const int* __restrict__ bsum,
                                              int* __restrict__ offsets,
                                              int* __restrict__ spack,
                                              int N, int E, int NBUK, int NBS) {
    __shared__ int sdeg[128], sincl[128], scur[128];
    __shared__ int ss[256];
    __shared__ int sbp[256];
    const int t = threadIdx.x, b = blockIdx.x;
    build_sbp(bsum, ss, sbp, NBS);
    int i0 = b << 8;
    int i1 = (b + 1) << 8;
    const int s0 = (i0 == 0) ? 0 : (tsc[i0 - 1] + sbp[(i0 - 1) >> 10]);
    const int s1 = tsc[i1 - 1] + sbp[(i1 - 1) >> 10];
    if (t < 128) { sdeg[t] = 0; }
    __syncthreads();
    for (int e = s0 + t; e < s1; e += 256)
        atomicAdd(&sdeg[((unsigned int)ebuf[e]) >> 25], 1);
    __syncthreads();
    if (t < 128) sincl[t] = sdeg[t];
    __syncthreads();
    for (int off = 1; off < 128; off <<= 1) {
        int v = 0;
        if (t < 128 && t >= off) v = sincl[t - off];
        __syncthreads();
        if (t < 128) sincl[t] += v;
        __syncthreads();
    }
    if (t < 128) {
        int excl = sincl[t] - sdeg[t];
        scur[t] = s0 + excl;
        int n = (b << 7) + t;
        if (n < N) offsets[n] = s0 + excl;
    }
    if (b == NBUK - 1 && t == 0) offsets[N] = E;
    __syncthreads();
    for (int e = s0 + t; e < s1; e += 256) {
        unsigned int pk = (unsigned int)ebuf[e];
        int i = pk >> 25;
        int p = atomicAdd(&scur[i], 1);
        spack[p] = (int)(pk & 0x01FFFFFFu);
    }
}

// ---------------- fused proj+V, r-quartered grid (tile x r-quarter blocks).
__global__ __launch_bounds__(256, 4) void k_projv(const unsigned short* __restrict__ fh,
                                                  const unsigned short* __restrict__ fl,
                                                  const unsigned short* __restrict__ B1h,
                                                  const unsigned short* __restrict__ B1l,
                                                  const unsigned short* __restrict__ B2h,
                                                  const unsigned short* __restrict__ B2l,
                                                  const float* __restrict__ emb,
                                                  unsigned short* __restrict__ V,
                                                  int N, int R, int nrq) {
    const int tile = blockIdx.x / nrq;
    const int rq   = blockIdx.x % nrq;
    const int rbase = rq * 4;
    const int rcnt  = (R - rbase < 4) ? (R - rbase) : 4;
    const int n0 = tile * 128;
    __shared__ __align__(16) unsigned short Bbuf[32][512];   // 32 KB
    __shared__ __align__(16) unsigned short Us[4][1024];     // 8 KB (per-s, wave-private)
    const int t = threadIdx.x;
    const int lane = t & 63, w = t >> 6;
    const int m = lane & 15, q = lane >> 4;

    // ---- A-frags: plain 16B loads of pre-split bf16 hi/lo
    bf16x8 ah[2][2], al[2][2];
    #pragma unroll
    for (int s = 0; s < 2; ++s) {
        int n = n0 + w * 32 + s * 16 + m;
        bool ok = n < N;
        #pragma unroll
        for (int kb = 0; kb < 2; ++kb) {
            int d0 = kb * 32 + q * 8;
            if (ok) {
                ah[s][kb] = *(const bf16x8*)&fh[(size_t)n * D + d0];
                al[s][kb] = *(const bf16x8*)&fl[(size_t)n * D + d0];
            } else {
                #pragma unroll
                for (int j = 0; j < 8; ++j) { ah[s][kb][j] = 0; al[s][kb][j] = 0; }
            }
        }
    }

    auto stage_half = [&](int r, int half) {
        const unsigned short* arr = half ? ((w < 2) ? B2h : B2l)
                                         : ((w < 2) ? B1h : B1l);
        const unsigned short* gp = arr + (size_t)r * 4096 + (size_t)(w & 1) * 2048 + lane * 8;
        unsigned short* lp = &Bbuf[half * 16 + (w >> 1) * 8 + (w & 1) * 4][0];
        #pragma unroll
        for (int i = 0; i < 4; ++i)
            dma16(gp + i * 512, lp + i * 512);
    };

    stage_half(rbase, 0);
    stage_half(rbase, 1);
    __syncthreads();

    for (int rr = 0; rr < rcnt; ++rr) {
        const int r = rbase + rr;
        float em[4];
        #pragma unroll
        for (int c = 0; c < 4; ++c) em[c] = emb[r * 64 + c * 16 + m];

        // ---------- GEMM1 (both s): P = feat @ W_r (3-term split), B-frags hoisted
        f32x4 acc[4][2];
        #pragma unroll
        for (int c = 0; c < 4; ++c)
            #pragma unroll
            for (int s = 0; s < 2; ++s) acc[c][s] = (f32x4){0.f, 0.f, 0.f, 0.f};
        #pragma unroll
        for (int c = 0; c < 4; ++c) {
            bf16x8 bh[2], bl[2];
            #pragma unroll
            for (int kb = 0; kb < 2; ++kb) {
                bh[kb] = *(const bf16x8*)&Bbuf[c * 2 + kb][lane * 8];
                bl[kb] = *(const bf16x8*)&Bbuf[8 + c * 2 + kb][lane * 8];
            }
            #pragma unroll
            for (int s = 0; s < 2; ++s)
                #pragma unroll
                for (int kb = 0; kb < 2; ++kb) {
                    acc[c][s] = __builtin_amdgcn_mfma_f32_16x16x32_bf16(ah[s][kb], bh[kb], acc[c][s], 0, 0, 0);
                    acc[c][s] = __builtin_amdgcn_mfma_f32_16x16x32_bf16(al[s][kb], bh[kb], acc[c][s], 0, 0, 0);
                    acc[c][s] = __builtin_amdgcn_mfma_f32_16x16x32_bf16(ah[s][kb], bl[kb], acc[c][s], 0, 0, 0);
                }
        }

        __syncthreads();                         // rows 0-15 consumed
        if (rr + 1 < rcnt) stage_half(r + 1, 0); // B1(r+1) DMA overlaps epi+GEMM2

        // ---------- per-s: epilogue -> Us, GEMM2, store
        #pragma unroll
        for (int s = 0; s < 2; ++s) {
            #pragma unroll
            for (int c = 0; c < 4; ++c) {
                int o = c * 16 + m;
                int kb2 = o >> 5;
                int q2 = (o >> 3) & 3;
                int j = o & 7;
                int Fb = kb2 * 64 + q2 * 16 + q * 4;
                #pragma unroll
                for (int i = 0; i < 4; i += 2) {
                    float t0 = fast_tanh(acc[c][s][i] + em[c]);
                    float t1 = fast_tanh(acc[c][s][i + 1] + em[c]);
                    unsigned int pk = pk2bf(t0, t1);
                    Us[w][((Fb + i) ^ q2) * 8 + j]     = (unsigned short)(pk & 0xFFFF);
                    Us[w][((Fb + i + 1) ^ q2) * 8 + j] = (unsigned short)(pk >> 16);
                }
            }

            bf16x8 ua[2];
            #pragma unroll
            for (int kb = 0; kb < 2; ++kb) {
                int F = kb * 64 + lane;
                ua[kb] = *(const bf16x8*)&Us[w][(F ^ (lane >> 4)) * 8];
            }
            f32x4 acc2[4];
            #pragma unroll
            for (int c = 0; c < 4; ++c) acc2[c] = (f32x4){0.f, 0.f, 0.f, 0.f};
            #pragma unroll
            for (int c = 0; c < 4; ++c) {
                bf16x8 bh[2], bl[2];
                #pragma unroll
                for (int kb = 0; kb < 2; ++kb) {
                    bh[kb] = *(const bf16x8*)&Bbuf[16 + c * 2 + kb][lane * 8];
                    bl[kb] = *(const bf16x8*)&Bbuf[24 + c * 2 + kb][lane * 8];
                }
                #pragma unroll
                for (int kb = 0; kb < 2; ++kb) {
                    acc2[c] = __builtin_amdgcn_mfma_f32_16x16x32_bf16(ua[kb], bh[kb], acc2[c], 0, 0, 0);
                    acc2[c] = __builtin_amdgcn_mfma_f32_16x16x32_bf16(ua[kb], bl[kb], acc2[c], 0, 0, 0);
                }
            }

            #pragma unroll
            for (int i = 0; i < 4; ++i) {
                int n = n0 + w * 32 + s * 16 + q * 4 + i;
                if (n < N) {
                    uint2 pv;
                    pv.x = pk2h(acc2[0][i], acc2[1][i]);   // fp16 pack (RTZ)
                    pv.y = pk2h(acc2[2][i], acc2[3][i]);
                    *(uint2*)&V[((size_t)n * R + r) * 64 + m * 4] = pv;
                }
            }
        }

        __syncthreads();                         // rows 16-31 consumed; half-0 DMA drained
        if (rr + 1 < rcnt) stage_half(r + 1, 1); // B2(r+1) DMA overlaps next GEMM1
    }
}

// ---------------- fused att + softmax + aggregation, v3 (measured best):
// V staged raw fp16 via global_load_lds; logit dot = 2x v_dot2_f32_f16;
// 16-edge chunks, two-phase softmax; lean LDS (8KB) + low VGPR for occupancy.
__global__ __launch_bounds__(256) void k_fused2(const unsigned short* __restrict__ V,
                                                const unsigned short* __restrict__ fb,
                                                const int* __restrict__ offsets,
                                                const int* __restrict__ spack,
                                                float* __restrict__ h_nb,
                                                int N, int R) {
    const int lane = threadIdx.x & 63;
    const int wav  = threadIdx.x >> 6;
    const int g    = lane >> 4;
    const int k    = lane & 15;
    const int n = blockIdx.x * 4 + wav;
    __shared__ __align__(16) unsigned short vlds[4][1024];   // 2KB raw fp16 V per wave

    if (n < N) {
        const unsigned short* gp = V + (size_t)n * 1024 + lane * 8;
        dma16(gp,       &vlds[wav][0]);
        dma16(gp + 512, &vlds[wav][512]);
    }
    __syncthreads();
    if (n >= N) return;

    const int beg = offsets[n], end = offsets[n + 1];
    float m = -INFINITY, l = 0.f;
    float4 acc = make_float4(0.f, 0.f, 0.f, 0.f);

    for (int cbeg = beg; cbeg < end; cbeg += 16) {
        // ---- pass 1: up to 16 logits (4 iters x 4 groups), dots via fdot2
        float pv0, pv1, pv2, pv3;
        uint2 gv0, gv1, gv2, gv3;
        #pragma unroll
        for (int it = 0; it < 4; ++it) {
            int e = cbeg + it * 4 + g;
            bool ok = e < end;
            int pk = spack[ok ? e : end - 1];
            unsigned int off32 = (unsigned int)(pk & 0xFFFFF) * D + k * 4;
            uint2 fvu = *(const uint2*)&fb[off32];
            int et = pk >> 20;
            uint2 vvu = *(const uint2*)&vlds[wav][et * 64 + k * 4];
            union { uint2 u; fp16x2 h[2]; } cf, vv;
            cf.u = fvu; vv.u = vvu;
            float d = __builtin_amdgcn_fdot2(cf.h[0], vv.h[0], 0.f, false);
            d = __builtin_amdgcn_fdot2(cf.h[1], vv.h[1], d, false);
            d += __shfl_xor(d, 1, 64);
            d += __shfl_xor(d, 2, 64);
            d += __shfl_xor(d, 4, 64);
            d += __shfl_xor(d, 8, 64);
            d = ok ? d : -INFINITY;
            if (it == 0) { pv0 = d; gv0 = fvu; }
            else if (it == 1) { pv1 = d; gv1 = fvu; }
            else if (it == 2) { pv2 = d; gv2 = fvu; }
            else { pv3 = d; gv3 = fvu; }
        }
        // ---- chunk max / sum (one wave-wide reduce per 16 edges)
        float cm = fmaxf(fmaxf(pv0, pv1), fmaxf(pv2, pv3));
        cm = fmaxf(cm, __shfl_xor(cm, 16, 64));
        cm = fmaxf(cm, __shfl_xor(cm, 32, 64));
        float nm = fmaxf(m, cm);
        float scale = __expf(m - nm);            // exp(-inf)=0 on first chunk
        float w0 = __expf(pv0 - nm);             // invalid lanes -> exp(-inf)=0
        float w1 = __expf(pv1 - nm);
        float w2 = __expf(pv2 - nm);
        float w3 = __expf(pv3 - nm);
        float cs = w0 + w1 + w2 + w3;
        cs += __shfl_xor(cs, 16, 64);
        cs += __shfl_xor(cs, 32, 64);
        l = l * scale + cs;
        // ---- pass 2: weighted accumulate from kept registers (v_fma_mix)
        acc.x *= scale; acc.y *= scale; acc.z *= scale; acc.w *= scale;
        {
            union { uint2 u; _Float16 h[4]; } c0, c1, c2, c3;
            c0.u = gv0; c1.u = gv1; c2.u = gv2; c3.u = gv3;
            acc.x += w0 * (float)c0.h[0] + w1 * (float)c1.h[0]
                   + w2 * (float)c2.h[0] + w3 * (float)c3.h[0];
            acc.y += w0 * (float)c0.h[1] + w1 * (float)c1.h[1]
                   + w2 * (float)c2.h[1] + w3 * (float)c3.h[1];
            acc.z += w0 * (float)c0.h[2] + w1 * (float)c1.h[2]
                   + w2 * (float)c2.h[2] + w3 * (float)c3.h[2];
            acc.w += w0 * (float)c0.h[3] + w1 * (float)c1.h[3]
                   + w2 * (float)c2.h[3] + w3 * (float)c3.h[3];
        }
        m = nm;
    }

    // cross-group reduce + normalize
    acc.x += __shfl_xor(acc.x, 16, 64);
    acc.y += __shfl_xor(acc.y, 16, 64);
    acc.z += __shfl_xor(acc.z, 16, 64);
    acc.w += __shfl_xor(acc.w, 16, 64);
    acc.x += __shfl_xor(acc.x, 32, 64);
    acc.y += __shfl_xor(acc.y, 32, 64);
    acc.z += __shfl_xor(acc.z, 32, 64);
    acc.w += __shfl_xor(acc.w, 32, 64);
    float inv = (l != 0.f) ? 1.f / l : 0.f;
    if (lane < 16) {
        // lane k holds permuted quad {c*16+k} -> natural-order coalesced stores
        h_nb[(size_t)n * D + 0 * 16 + k] = acc.x * inv;
        h_nb[(size_t)n * D + 1 * 16 + k] = acc.y * inv;
        h_nb[(size_t)n * D + 2 * 16 + k] = acc.z * inv;
        h_nb[(size_t)n * D + 3 * 16 + k] = acc.w * inv;
    }
}

// ---------------- final via MFMA: out = lrelu((f+h)@W1^T) + lrelu((f*h)@W2^T)
__global__ __launch_bounds__(256, 2) void k_final(const float* __restrict__ feat,
                                                  const float* __restrict__ h_nb,
                                                  const unsigned short* __restrict__ F1h,
                                                  const unsigned short* __restrict__ F1l,
                                                  const unsigned short* __restrict__ F2h,
                                                  const unsigned short* __restrict__ F2l,
                                                  float* __restrict__ out, int N) {
    const int n0 = blockIdx.x * 128;
    __shared__ __align__(16) unsigned short Wlds[4][4096];
    const int t = threadIdx.x;
    const int lane = t & 63, w = t >> 6;
    const int m = lane & 15, q = lane >> 4;

    const unsigned short* warr = (w == 0) ? F1h : (w == 1) ? F1l : (w == 2) ? F2h : F2l;
    #pragma unroll
    for (int i = 0; i < 8; ++i)
        dma16(warr + i * 512 + lane * 8, &Wlds[w][i * 512]);

    bf16x8 sh[2][2], sl[2][2], ph[2][2], pl[2][2];
    #pragma unroll
    for (int s = 0; s < 2; ++s) {
        int n = n0 + w * 32 + s * 16 + m;
        const float* fp = feat + (size_t)n * D;
        const float* hp = h_nb + (size_t)n * D;
        #pragma unroll
        for (int kb = 0; kb < 2; ++kb) {
            int d0 = kb * 32 + q * 8;
            float4 f0 = make_float4(0.f, 0.f, 0.f, 0.f), f1 = f0, h0 = f0, h1 = f0;
            if (n < N) {
                f0 = *(const float4*)(fp + d0); f1 = *(const float4*)(fp + d0 + 4);
                h0 = *(const float4*)(hp + d0); h1 = *(const float4*)(hp + d0 + 4);
            }
            float fv[8] = {f0.x, f0.y, f0.z, f0.w, f1.x, f1.y, f1.z, f1.w};
            float hv[8] = {h0.x, h0.y, h0.z, h0.w, h1.x, h1.y, h1.z, h1.w};
            bf16x8 a, b, c2, d2;
            #pragma unroll
            for (int j = 0; j < 8; ++j) {
                float xs = fv[j] + hv[j];
                float xp = fv[j] * hv[j];
                unsigned short hs = f2bf(xs);
                unsigned short hp2 = f2bf(xp);
                a[j]  = (short)hs;
                b[j]  = (short)f2bf(xs - bf2f(hs));
                c2[j] = (short)hp2;
                d2[j] = (short)f2bf(xp - bf2f(hp2));
            }
            sh[s][kb] = a; sl[s][kb] = b; ph[s][kb] = c2; pl[s][kb] = d2;
        }
    }
    __syncthreads();

    f32x4 a1[4][2], a2[4][2];
    #pragma unroll
    for (int c = 0; c < 4; ++c)
        #pragma unroll
        for (int s = 0; s < 2; ++s) {
            a1[c][s] = (f32x4){0.f, 0.f, 0.f, 0.f};
            a2[c][s] = (f32x4){0.f, 0.f, 0.f, 0.f};
        }
    #pragma unroll
    for (int c = 0; c < 4; ++c) {
        bf16x8 b1h[2], b1l[2], b2h[2], b2l[2];
        #pragma unroll
        for (int kb = 0; kb < 2; ++kb) {
            int o = (c * 2 + kb) * 512 + lane * 8;
            b1h[kb] = *(const bf16x8*)&Wlds[0][o];
            b1l[kb] = *(const bf16x8*)&Wlds[1][o];
            b2h[kb] = *(const bf16x8*)&Wlds[2][o];
            b2l[kb] = *(const bf16x8*)&Wlds[3][o];
        }
        #pragma unroll
        for (int kb = 0; kb < 2; ++kb)
            #pragma unroll
            for (int s = 0; s < 2; ++s) {
                a1[c][s] = __builtin_amdgcn_mfma_f32_16x16x32_bf16(sh[s][kb], b1h[kb], a1[c][s], 0, 0, 0);
                a1[c][s] = __builtin_amdgcn_mfma_f32_16x16x32_bf16(sl[s][kb], b1h[kb], a1[c][s], 0, 0, 0);
                a1[c][s] = __builtin_amdgcn_mfma_f32_16x16x32_bf16(sh[s][kb], b1l[kb], a1[c][s], 0, 0, 0);
                a2[c][s] = __builtin_amdgcn_mfma_f32_16x16x32_bf16(ph[s][kb], b2h[kb], a2[c][s], 0, 0, 0);
                a2[c][s] = __builtin_amdgcn_mfma_f32_16x16x32_bf16(pl[s][kb], b2h[kb], a2[c][s], 0, 0, 0);
                a2[c][s] = __builtin_amdgcn_mfma_f32_16x16x32_bf16(ph[s][kb], b2l[kb], a2[c][s], 0, 0, 0);
            }
    }

    #pragma unroll
    for (int s = 0; s < 2; ++s)
        #pragma unroll
        for (int i = 0; i < 4; ++i) {
            int n = n0 + w * 32 + s * 16 + q * 4 + i;
            if (n < N) {
                #pragma unroll
                for (int c = 0; c < 4; ++c) {
                    float o1 = a1[c][s][i];
                    float o2 = a2[c][s][i];
                    o1 = (o1 > 0.f) ? o1 : 0.01f * o1;
                    o2 = (o2 > 0.f) ? o2 : 0.01f * o2;
                    out[(size_t)n * D + c * 16 + m] = o1 + o2;
                }
            }
        }
}

extern "C" void kernel_launch(void* const* d_in, const int* in_sizes, int n_in,
                              void* d_out, int out_size, void* d_ws, size_t ws_size,
                              hipStream_t stream) {
    const float* feat  = (const float*)d_in[0];
    const float* relW  = (const float*)d_in[1];
    const float* relE  = (const float*)d_in[2];
    const float* W1    = (const float*)d_in[3];
    const float* W2    = (const float*)d_in[4];
    const int*   src   = (const int*)d_in[5];
    const int*   dst   = (const int*)d_in[6];
    const int*   etype = (const int*)d_in[7];
    float* out = (float*)d_out;

    const int N = in_sizes[0] / D;
    const int R = in_sizes[2] / D;
    const int E = in_sizes[5];

    char* w = (char*)d_ws;
    size_t off = 0;
    auto alloc = [&](size_t bytes) -> void* {
        void* p = w + off;
        off = (off + bytes + 255) & ~(size_t)255;
        return p;
    };
    unsigned short* varr = (unsigned short*)alloc((size_t)N * R * D * sizeof(unsigned short));
    float* h_nb   = (float*)alloc((size_t)N * D * sizeof(float));
    int* offsets  = (int*)alloc((size_t)(N + 1) * sizeof(int));
    int* bsum     = (int*)alloc(2048 * sizeof(int));
    int* spack    = (int*)alloc((size_t)E * sizeof(int));
    unsigned short* fb = (unsigned short*)alloc((size_t)N * D * sizeof(unsigned short));
    size_t wfrag = (size_t)R * 4 * 2 * 64 * 8;
    unsigned short* B1h = (unsigned short*)alloc(wfrag * sizeof(unsigned short));
    unsigned short* B1l = (unsigned short*)alloc(wfrag * sizeof(unsigned short));
    unsigned short* B2h = (unsigned short*)alloc(wfrag * sizeof(unsigned short));
    unsigned short* B2l = (unsigned short*)alloc(wfrag * sizeof(unsigned short));
    unsigned short* F1h = (unsigned short*)alloc(4096 * sizeof(unsigned short));
    unsigned short* F1l = (unsigned short*)alloc(4096 * sizeof(unsigned short));
    unsigned short* F2h = (unsigned short*)alloc(4096 * sizeof(unsigned short));
    unsigned short* F2l = (unsigned short*)alloc(4096 * sizeof(unsigned short));
    (void)ws_size; (void)n_in; (void)out_size;

    // ---- fh/fl (bf16 hi/lo feat) alias h_nb (dead until k_fused2 writes it)
    unsigned short* fh = (unsigned short*)h_nb;            // N*D shorts
    unsigned short* fl = fh + (size_t)N * D;               // N*D shorts

    // ---- CSR scratch aliases varr (dead before k_projv writes varr)
    const int NBUK = (N + 127) >> 7;           // buckets of 128 nodes (<=1024)
    const int CH   = (E + NB3 - 1) / NB3;      // edges per chunk
    const int L    = NBUK << 8;                // cnt length (NB3=256)
    int* ebuf = (int*)varr;                    // E ints
    int* cnt  = ebuf + E;                      // L ints
    int* tsc  = cnt + L;                       // L ints
    const int NBscan = (L + 1023) / 1024;      // <=256 (NBUK<=1024)

    const int nrq = (R + 3) / 4;               // r-quarters per tile
    const int ntiles = (N + 127) / 128;
    const int nPrep = N * 16 + N * 8 + 2 * R * 512 + 1024;
    const int PB = (nPrep + 255) / 256;

    k_prep<<<PB + NB3, 256, 0, stream>>>(relW, B1h, B1l, B2h, B2l,
                                         W1, W2, F1h, F1l, F2h, F2l,
                                         feat, fb, fh, fl,
                                         dst, cnt, R, N, E, CH, NBUK, PB);
    k_scan1<<<NBscan, 1024, 0, stream>>>(cnt, tsc, bsum, L);
    k_bscatter<<<NB3, 256, 0, stream>>>(src, dst, etype, tsc, bsum, ebuf, E, CH, NBUK, NBscan);
    k_bcsr<<<NBUK, 256, 0, stream>>>(ebuf, tsc, bsum, offsets, spack, N, E, NBUK, NBscan);
    k_projv<<<ntiles * nrq, 256, 0, stream>>>(fh, fl, B1h, B1l, B2h, B2l, relE, varr, N, R, nrq);
    k_fused2<<<(N + 3) / 4, 256, 0, stream>>>(varr, fb, offsets, spack, h_nb, N, R);
    k_final<<<(N + 127) / 128, 256, 0, stream>>>(feat, h_nb, F1h, F1l, F2h, F2l, out, N);
}